// Round 10
// baseline (1762.089 us; speedup 1.0000x reference)
//
#include <hip/hip_runtime.h>
#include <hip/hip_bf16.h>

#define Bn  512
#define Sn  30
#define Dm  300
#define Hn  20
#define DHn 20
#define AHn 200
#define HDn 400
#define EQn 6000

// ---------------------------------------------------------------------------
// k_c: c[bl][s][d] = emb[x[b0+bl][s]][d] + PE(s,d)
// ---------------------------------------------------------------------------
__global__ __launch_bounds__(256) void k_c(const int* __restrict__ x,
        const float* __restrict__ emb, float* __restrict__ c, int b0, int nloc)
{
    int n = nloc * Sn * Dm;
    for (int p = blockIdx.x * 256 + threadIdx.x; p < n; p += gridDim.x * 256) {
        int bl = p / (Sn * Dm);
        int r  = p - bl * (Sn * Dm);
        int s = r / Dm, d = r - s * Dm;
        int tok = x[(b0 + bl) * Sn + s];
        float dv = expf(-0.06140226914650789f * (float)(d >> 1));
        float ang = (float)s * dv;
        c[p] = emb[(size_t)tok * Dm + d] + ((d & 1) ? cosf(ang) : sinf(ang));
    }
}

// ---------------------------------------------------------------------------
// k_xq: xq[m][n] = c[m][:].Wq[n][:] + bq[n]
// ---------------------------------------------------------------------------
#define TBM 64
#define TBN 64
#define TBK 30
__global__ __launch_bounds__(256) void k_xq(const float* __restrict__ c,
        const float* __restrict__ Wq, const float* __restrict__ bq,
        float* __restrict__ xq, int Mloc)
{
    __shared__ __attribute__((aligned(16))) float Ast[TBK][TBM + 4];
    __shared__ __attribute__((aligned(16))) float Bst[TBK][TBN + 4];
    int t = threadIdx.x;
    int tx = t & 15, ty = t >> 4;
    int m0 = blockIdx.y * TBM, n0 = blockIdx.x * TBN;
    float acc[4][4] = {};
    for (int k0 = 0; k0 < Dm; k0 += TBK) {
        for (int i = t; i < TBM * TBK; i += 256) {
            int m = i / TBK, k = i - m * TBK;
            int gm = m0 + m;
            Ast[k][m] = (gm < Mloc) ? c[(size_t)gm * Dm + k0 + k] : 0.f;
        }
        for (int i = t; i < TBN * TBK; i += 256) {
            int n = i / TBK, k = i - n * TBK;
            int gn = n0 + n;
            Bst[k][n] = (gn < EQn) ? Wq[(size_t)gn * Dm + k0 + k] : 0.f;
        }
        __syncthreads();
        #pragma unroll
        for (int k = 0; k < TBK; k++) {
            float4 a4 = *(const float4*)&Ast[k][ty * 4];
            float4 b4 = *(const float4*)&Bst[k][tx * 4];
            float ar[4] = {a4.x, a4.y, a4.z, a4.w};
            float br[4] = {b4.x, b4.y, b4.z, b4.w};
            #pragma unroll
            for (int r = 0; r < 4; r++)
                #pragma unroll
                for (int cn = 0; cn < 4; cn++)
                    acc[r][cn] += ar[r] * br[cn];
        }
        __syncthreads();
    }
    #pragma unroll
    for (int r = 0; r < 4; r++) {
        int gm = m0 + ty * 4 + r;
        if (gm >= Mloc) continue;
        #pragma unroll
        for (int cn = 0; cn < 4; cn++) {
            int gn = n0 + tx * 4 + cn;
            if (gn < EQn)
                xq[(size_t)gm * EQn + gn] = acc[r][cn] + bq[gn];
        }
    }
}

// ---------------------------------------------------------------------------
// k_xv: xv[bl][s][e] = c[bl][s][:].Wv[e][:] + bv[e]
// ---------------------------------------------------------------------------
__global__ __launch_bounds__(256) void k_xv(const float* __restrict__ c,
        const float* __restrict__ Wv, const float* __restrict__ bv,
        float* __restrict__ xv)
{
    __shared__ __attribute__((aligned(16))) float cb[Sn * Dm];
    int bl = blockIdx.x, t = threadIdx.x;
    for (int i = t; i < Sn * Dm; i += 256) cb[i] = c[(size_t)bl * Sn * Dm + i];
    __syncthreads();
    if (t < 200) {
        int e0 = (t % 100) * 4;
        int s0 = (t / 100) * 15;
        float acc[15][4];
        #pragma unroll
        for (int si = 0; si < 15; ++si)
            #pragma unroll
            for (int ee = 0; ee < 4; ++ee) acc[si][ee] = 0.f;
        for (int k = 0; k < Dm; k += 4) {
            float4 w0 = *(const float4*)&Wv[(size_t)(e0 + 0) * Dm + k];
            float4 w1 = *(const float4*)&Wv[(size_t)(e0 + 1) * Dm + k];
            float4 w2 = *(const float4*)&Wv[(size_t)(e0 + 2) * Dm + k];
            float4 w3 = *(const float4*)&Wv[(size_t)(e0 + 3) * Dm + k];
            #pragma unroll
            for (int si = 0; si < 15; ++si) {
                float4 cv = *(const float4*)&cb[(s0 + si) * Dm + k];
                acc[si][0] += cv.x*w0.x + cv.y*w0.y + cv.z*w0.z + cv.w*w0.w;
                acc[si][1] += cv.x*w1.x + cv.y*w1.y + cv.z*w1.z + cv.w*w1.w;
                acc[si][2] += cv.x*w2.x + cv.y*w2.y + cv.z*w2.z + cv.w*w2.w;
                acc[si][3] += cv.x*w3.x + cv.y*w3.y + cv.z*w3.z + cv.w*w3.w;
            }
        }
        #pragma unroll
        for (int si = 0; si < 15; ++si)
            #pragma unroll
            for (int ee = 0; ee < 4; ++ee)
                xv[(size_t)bl * (Sn * HDn) + (s0 + si) * HDn + e0 + ee]
                    = acc[si][ee] + bv[e0 + ee];
    }
}

// ---------------------------------------------------------------------------
// k_attn: one block per (h, bl). FAITHFUL raw-reshape indexing (displayed jax):
//   Q(i,d) = xq[bl*180000 + h*9000 + i*300 + d]
//   K(d,j) = c [bl*9000  + d*30 + j]
//   w[i][j] = sum_d Q K ; softmax over i (axis=-2, per column j); hout = w @ V
//   V(j,k)  = xv[bl*12000 + h*600 + j*20 + k]
//   h2[bl*12000 + h*600 + i*20 + k] = hout
// ---------------------------------------------------------------------------
__global__ __launch_bounds__(256) void k_attn(const float* __restrict__ c,
        const float* __restrict__ xq, const float* __restrict__ xv,
        float* __restrict__ h2)
{
    __shared__ __attribute__((aligned(16))) float qs[Sn * Dm];
    __shared__ __attribute__((aligned(16))) float kb[Sn * Dm];
    __shared__ float wm[Sn * Sn];
    __shared__ float vm[Sn * DHn];
    int h = blockIdx.x, bl = blockIdx.y, t = threadIdx.x;

    const float* qsrc = xq + (size_t)bl * (Sn * EQn) + (size_t)h * (Sn * Dm);
    for (int i = t; i < Sn * Dm; i += 256) qs[i] = qsrc[i];
    for (int i = t; i < Sn * Dm; i += 256) kb[i] = c[(size_t)bl * (Sn * Dm) + i];
    for (int i = t; i < Sn * DHn; i += 256)
        vm[i] = xv[(size_t)bl * (Sn * HDn) + h * (Sn * DHn) + i];
    __syncthreads();

    // scores: wm[i][j] = sum_d Q(i,d) K(d,j),  K(d,j) = kb[d*30+j]
    for (int p = t; p < Sn * Sn; p += 256) {
        int i = p / Sn, j = p - i * Sn;
        float acc = 0.f;
        for (int d = 0; d < Dm; ++d) acc += qs[i * Dm + d] * kb[d * Sn + j];
        wm[p] = acc;
    }
    __syncthreads();

    // softmax over query dim i (axis=-2), per column j
    if (t < Sn) {
        int j = t;
        float mx = -1e30f;
        for (int i = 0; i < Sn; ++i) mx = fmaxf(mx, wm[i * Sn + j]);
        float sum = 0.f;
        for (int i = 0; i < Sn; ++i) {
            float e = expf(wm[i * Sn + j] - mx);
            wm[i * Sn + j] = e; sum += e;
        }
        float inv = 1.f / sum;
        for (int i = 0; i < Sn; ++i) wm[i * Sn + j] *= inv;
    }
    __syncthreads();

    // PV
    for (int p = t; p < Sn * DHn; p += 256) {
        int i = p / DHn, k = p - i * DHn;
        float acc = 0.f;
        #pragma unroll
        for (int j = 0; j < Sn; ++j) acc += wm[i * Sn + j] * vm[j * DHn + k];
        h2[(size_t)bl * (Sn * HDn) + (size_t)h * (Sn * DHn) + p] = acc;
    }
}

// ---------------------------------------------------------------------------
// k_pool: additive pooling per bl -> out[(b0+bl)][400]  (*** FLOAT32 out ***)
// ---------------------------------------------------------------------------
__global__ __launch_bounds__(256) void k_pool(const float* __restrict__ h2,
        const float* __restrict__ WVm, const float* __restrict__ bV,
        const float* __restrict__ wq2, const float* __restrict__ bq2,
        float* __restrict__ out, int b0)
{
    __shared__ __attribute__((aligned(16))) float hb[Sn * HDn];
    __shared__ float wpart[4][Sn];
    __shared__ float psm[Sn];
    int bl = blockIdx.x, t = threadIdx.x;
    for (int i = t; i < Sn * HDn; i += 256) hb[i] = h2[(size_t)bl * (Sn * HDn) + i];
    __syncthreads();

    int u = (t < AHn) ? t : AHn - 1;
    float acc[Sn];
    #pragma unroll
    for (int s = 0; s < Sn; ++s) acc[s] = 0.f;
    for (int k = 0; k < HDn; k += 4) {
        float4 wv = *(const float4*)&WVm[(size_t)u * HDn + k];
        #pragma unroll
        for (int s = 0; s < Sn; ++s) {
            float4 hv = *(const float4*)&hb[s * HDn + k];
            acc[s] += hv.x*wv.x + hv.y*wv.y + hv.z*wv.z + hv.w*wv.w;
        }
    }
    float bias = bV[u];
    float wqv  = wq2[u];
    float mask = (t < AHn) ? 1.f : 0.f;
    int wid = t >> 6;
    #pragma unroll
    for (int s = 0; s < Sn; ++s) {
        float v = tanhf(acc[s] + bias) * wqv * mask;
        #pragma unroll
        for (int off = 32; off > 0; off >>= 1) v += __shfl_xor(v, off);
        if ((t & 63) == 0) wpart[wid][s] = v;
    }
    __syncthreads();
    if (t == 0) {
        float b2 = bq2[0];
        float sc[Sn], mx = -1e30f;
        for (int s = 0; s < Sn; ++s) {
            sc[s] = wpart[0][s] + wpart[1][s] + wpart[2][s] + wpart[3][s] + b2;
            mx = fmaxf(mx, sc[s]);
        }
        float sum = 0.f;
        for (int s = 0; s < Sn; ++s) { float e = expf(sc[s] - mx); psm[s] = e; sum += e; }
        float inv = 1.f / sum;
        for (int s = 0; s < Sn; ++s) psm[s] *= inv;
    }
    __syncthreads();
    for (int e = t; e < HDn; e += 256) {
        float z = 0.f;
        #pragma unroll
        for (int s = 0; s < Sn; ++s) z += psm[s] * hb[s * HDn + e];
        out[(size_t)(b0 + bl) * HDn + e] = z;   // f32 store
    }
}

// ---------------------------------------------------------------------------
extern "C" void kernel_launch(void* const* d_in, const int* in_sizes, int n_in,
                              void* d_out, int out_size, void* d_ws, size_t ws_size,
                              hipStream_t stream)
{
    const int*   x   = (const int*)d_in[0];
    const float* emb = (const float*)d_in[1];
    const float* Wq  = (const float*)d_in[2];
    const float* bq  = (const float*)d_in[3];
    const float* Wv  = (const float*)d_in[4];
    const float* bv  = (const float*)d_in[5];
    const float* WVm = (const float*)d_in[6];
    const float* bV  = (const float*)d_in[7];
    const float* wq2 = (const float*)d_in[8];
    const float* bq2 = (const float*)d_in[9];
    float* outp = (float*)d_out;   // *** reference output dtype: float32 ***

    // per-b ws: c 36000 + xq 720000 + xv 48000 + h2 48000 = 852000 B
    int CB = Bn;
    while (CB > 1 && (size_t)CB * 852000ull > ws_size) CB >>= 1;

    char* ws = (char*)d_ws;
    float* c  = (float*)(ws);
    float* xq = (float*)(ws + (size_t)CB * 36000ull);
    float* xv = (float*)(ws + (size_t)CB * 756000ull);
    float* h2 = (float*)(ws + (size_t)CB * 804000ull);

    for (int b0 = 0; b0 < Bn; b0 += CB) {
        int nloc = (b0 + CB <= Bn) ? CB : (Bn - b0);
        int Mloc = nloc * Sn;
        int gc = (nloc * Sn * Dm + 255) / 256;
        if (gc > 2048) gc = 2048;
        k_c<<<dim3(gc), dim3(256), 0, stream>>>(x, emb, c, b0, nloc);
        dim3 gq((EQn + TBN - 1) / TBN, (Mloc + TBM - 1) / TBM);
        k_xq<<<gq, dim3(256), 0, stream>>>(c, Wq, bq, xq, Mloc);
        k_xv<<<dim3(nloc), dim3(256), 0, stream>>>(c, Wv, bv, xv);
        k_attn<<<dim3(Hn, nloc), dim3(256), 0, stream>>>(c, xq, xv, h2);
        k_pool<<<dim3(nloc), dim3(256), 0, stream>>>(h2, WVm, bV, wq2, bq2, outp, b0);
    }
}

// Round 11
// 1015.270 us; speedup vs baseline: 1.7356x; 1.7356x over previous
//
#include <hip/hip_runtime.h>
#include <hip/hip_bf16.h>

#define Bn  512
#define Sn  30
#define Dm  300
#define Hn  20
#define DHn 20
#define AHn 200
#define HDn 400
#define EQn 6000
#define KP  320           // K padded to 10*32
#define NP  6016          // N padded to 47*128

typedef __attribute__((ext_vector_type(8))) short short8;
typedef __attribute__((ext_vector_type(4))) float f32x4;

// ---------------------------------------------------------------------------
// k_c: c[bl][s][d] = emb[x[b0+bl][s]][d] + PE(s,d)
// ---------------------------------------------------------------------------
__global__ __launch_bounds__(256) void k_c(const int* __restrict__ x,
        const float* __restrict__ emb, float* __restrict__ c, int b0, int nloc)
{
    int n = nloc * Sn * Dm;
    for (int p = blockIdx.x * 256 + threadIdx.x; p < n; p += gridDim.x * 256) {
        int bl = p / (Sn * Dm);
        int r  = p - bl * (Sn * Dm);
        int s = r / Dm, d = r - s * Dm;
        int tok = x[(b0 + bl) * Sn + s];
        float dv = expf(-0.06140226914650789f * (float)(d >> 1));
        float ang = (float)s * dv;
        c[p] = emb[(size_t)tok * Dm + d] + ((d & 1) ? cosf(ang) : sinf(ang));
    }
}

// ---------------------------------------------------------------------------
// k_cast_wq: Wqb[NP][KP] = bf16(Wq[n][k]) zero-padded   (once per launch)
// ---------------------------------------------------------------------------
__global__ __launch_bounds__(256) void k_cast_wq(const float* __restrict__ Wq,
        unsigned short* __restrict__ Wqb)
{
    for (int p = blockIdx.x * 256 + threadIdx.x; p < NP * KP; p += gridDim.x * 256) {
        int nq = p / KP, k = p - nq * KP;
        float v = (nq < EQn && k < Dm) ? Wq[(size_t)nq * Dm + k] : 0.f;
        __hip_bfloat16 h = __float2bfloat16(v);
        Wqb[p] = *(unsigned short*)&h;
    }
}

// ---------------------------------------------------------------------------
// k_cast_c: cbf[Mloc][KP] = bf16(c[m][k]) zero-padded   (per chunk)
// ---------------------------------------------------------------------------
__global__ __launch_bounds__(256) void k_cast_c(const float* __restrict__ c,
        unsigned short* __restrict__ cbf, int Mloc)
{
    int n = Mloc * KP;
    for (int p = blockIdx.x * 256 + threadIdx.x; p < n; p += gridDim.x * 256) {
        int m = p / KP, k = p - m * KP;
        float v = (k < Dm) ? c[(size_t)m * Dm + k] : 0.f;
        __hip_bfloat16 h = __float2bfloat16(v);
        cbf[p] = *(unsigned short*)&h;
    }
}

// ---------------------------------------------------------------------------
// k_xqm: xq[m][n] = sum_k cbf[m][k]*Wqb[n][k] + bq[n]   (bf16 MFMA, f32 acc)
// 128x128 tile, 4 waves (2x2 of 64x64), mfma_f32_16x16x32_bf16, BK=64
// LDS rows padded to 72 elems (144 B, coprime w/ 32 banks -> <=2-way, free)
// ---------------------------------------------------------------------------
__global__ __launch_bounds__(256) void k_xqm(const unsigned short* __restrict__ Ab,
        const unsigned short* __restrict__ Bb, const float* __restrict__ bq,
        float* __restrict__ xq, int Mloc)
{
    __shared__ __attribute__((aligned(16))) unsigned short As[128][72];
    __shared__ __attribute__((aligned(16))) unsigned short Bs[128][72];
    int t = threadIdx.x;
    int l = t & 63, w = t >> 6;
    int wm = w >> 1, wn = w & 1;
    int m0 = blockIdx.y * 128, n0 = blockIdx.x * 128;
    int cl = l & 15, rh = l >> 4;

    f32x4 zero4 = {0.f, 0.f, 0.f, 0.f};
    f32x4 acc[4][4];
    #pragma unroll
    for (int a = 0; a < 4; ++a)
        #pragma unroll
        for (int bb = 0; bb < 4; ++bb) acc[a][bb] = zero4;

    for (int k0 = 0; k0 < KP; k0 += 64) {
        #pragma unroll
        for (int cc = 0; cc < 4; ++cc) {
            int q = t + 256 * cc;           // 1024 chunks of 8 bf16
            int row = q >> 3, kc = (q & 7) * 8;
            int gm = m0 + row;
            short8 av = {0, 0, 0, 0, 0, 0, 0, 0};
            if (gm < Mloc) av = *(const short8*)&Ab[(size_t)gm * KP + k0 + kc];
            *(short8*)&As[row][kc] = av;
            short8 bv = *(const short8*)&Bb[(size_t)(n0 + row) * KP + k0 + kc];
            *(short8*)&Bs[row][kc] = bv;
        }
        __syncthreads();
        #pragma unroll
        for (int k2 = 0; k2 < 2; ++k2) {
            int kk = k2 * 32 + rh * 8;
            short8 af[4], bf[4];
            #pragma unroll
            for (int f = 0; f < 4; ++f) {
                af[f] = *(const short8*)&As[wm * 64 + f * 16 + cl][kk];
                bf[f] = *(const short8*)&Bs[wn * 64 + f * 16 + cl][kk];
            }
            #pragma unroll
            for (int mf = 0; mf < 4; ++mf)
                #pragma unroll
                for (int nf = 0; nf < 4; ++nf)
                    acc[mf][nf] = __builtin_amdgcn_mfma_f32_16x16x32_bf16(
                        af[mf], bf[nf], acc[mf][nf], 0, 0, 0);
        }
        __syncthreads();
    }

    // epilogue: C/D mapping col=lane&15, row=(lane>>4)*4+reg  [m89-verified]
    #pragma unroll
    for (int nf = 0; nf < 4; ++nf) {
        int gn = n0 + wn * 64 + nf * 16 + cl;
        float bqv = (gn < EQn) ? bq[gn] : 0.f;
        #pragma unroll
        for (int mf = 0; mf < 4; ++mf) {
            int gmb = m0 + wm * 64 + mf * 16 + rh * 4;
            #pragma unroll
            for (int r = 0; r < 4; ++r) {
                int gm = gmb + r;
                if (gm < Mloc && gn < EQn)
                    xq[(size_t)gm * EQn + gn] = acc[mf][nf][r] + bqv;
            }
        }
    }
}

// ---------------------------------------------------------------------------
// k_xv: xv[bl][s][e] = c[bl][s][:].Wv[e][:] + bv[e]
// ---------------------------------------------------------------------------
__global__ __launch_bounds__(256) void k_xv(const float* __restrict__ c,
        const float* __restrict__ Wv, const float* __restrict__ bv,
        float* __restrict__ xv)
{
    __shared__ __attribute__((aligned(16))) float cb[Sn * Dm];
    int bl = blockIdx.x, t = threadIdx.x;
    for (int i = t; i < Sn * Dm; i += 256) cb[i] = c[(size_t)bl * Sn * Dm + i];
    __syncthreads();
    if (t < 200) {
        int e0 = (t % 100) * 4;
        int s0 = (t / 100) * 15;
        float acc[15][4];
        #pragma unroll
        for (int si = 0; si < 15; ++si)
            #pragma unroll
            for (int ee = 0; ee < 4; ++ee) acc[si][ee] = 0.f;
        for (int k = 0; k < Dm; k += 4) {
            float4 w0 = *(const float4*)&Wv[(size_t)(e0 + 0) * Dm + k];
            float4 w1 = *(const float4*)&Wv[(size_t)(e0 + 1) * Dm + k];
            float4 w2 = *(const float4*)&Wv[(size_t)(e0 + 2) * Dm + k];
            float4 w3 = *(const float4*)&Wv[(size_t)(e0 + 3) * Dm + k];
            #pragma unroll
            for (int si = 0; si < 15; ++si) {
                float4 cv = *(const float4*)&cb[(s0 + si) * Dm + k];
                acc[si][0] += cv.x*w0.x + cv.y*w0.y + cv.z*w0.z + cv.w*w0.w;
                acc[si][1] += cv.x*w1.x + cv.y*w1.y + cv.z*w1.z + cv.w*w1.w;
                acc[si][2] += cv.x*w2.x + cv.y*w2.y + cv.z*w2.z + cv.w*w2.w;
                acc[si][3] += cv.x*w3.x + cv.y*w3.y + cv.z*w3.z + cv.w*w3.w;
            }
        }
        #pragma unroll
        for (int si = 0; si < 15; ++si)
            #pragma unroll
            for (int ee = 0; ee < 4; ++ee)
                xv[(size_t)bl * (Sn * HDn) + (s0 + si) * HDn + e0 + ee]
                    = acc[si][ee] + bv[e0 + ee];
    }
}

// ---------------------------------------------------------------------------
// k_attn: one block per (h, bl). Faithful raw-reshape indexing.
// ---------------------------------------------------------------------------
__global__ __launch_bounds__(256) void k_attn(const float* __restrict__ c,
        const float* __restrict__ xq, const float* __restrict__ xv,
        float* __restrict__ h2)
{
    __shared__ __attribute__((aligned(16))) float qs[Sn * Dm];
    __shared__ __attribute__((aligned(16))) float kb[Sn * Dm];
    __shared__ float wm[Sn * Sn];
    __shared__ float vm[Sn * DHn];
    int h = blockIdx.x, bl = blockIdx.y, t = threadIdx.x;

    const float* qsrc = xq + (size_t)bl * (Sn * EQn) + (size_t)h * (Sn * Dm);
    for (int i = t; i < Sn * Dm; i += 256) qs[i] = qsrc[i];
    for (int i = t; i < Sn * Dm; i += 256) kb[i] = c[(size_t)bl * (Sn * Dm) + i];
    for (int i = t; i < Sn * DHn; i += 256)
        vm[i] = xv[(size_t)bl * (Sn * HDn) + h * (Sn * DHn) + i];
    __syncthreads();

    for (int p = t; p < Sn * Sn; p += 256) {
        int i = p / Sn, j = p - i * Sn;
        float acc = 0.f;
        for (int d = 0; d < Dm; ++d) acc += qs[i * Dm + d] * kb[d * Sn + j];
        wm[p] = acc;
    }
    __syncthreads();

    // softmax over query dim i (axis=-2), per column j
    if (t < Sn) {
        int j = t;
        float mx = -1e30f;
        for (int i = 0; i < Sn; ++i) mx = fmaxf(mx, wm[i * Sn + j]);
        float sum = 0.f;
        for (int i = 0; i < Sn; ++i) {
            float e = expf(wm[i * Sn + j] - mx);
            wm[i * Sn + j] = e; sum += e;
        }
        float inv = 1.f / sum;
        for (int i = 0; i < Sn; ++i) wm[i * Sn + j] *= inv;
    }
    __syncthreads();

    for (int p = t; p < Sn * DHn; p += 256) {
        int i = p / DHn, k = p - i * DHn;
        float acc = 0.f;
        #pragma unroll
        for (int j = 0; j < Sn; ++j) acc += wm[i * Sn + j] * vm[j * DHn + k];
        h2[(size_t)bl * (Sn * HDn) + (size_t)h * (Sn * DHn) + p] = acc;
    }
}

// ---------------------------------------------------------------------------
// k_pool: additive pooling per bl -> out[(b0+bl)][400]  (f32 out)
// ---------------------------------------------------------------------------
__global__ __launch_bounds__(256) void k_pool(const float* __restrict__ h2,
        const float* __restrict__ WVm, const float* __restrict__ bV,
        const float* __restrict__ wq2, const float* __restrict__ bq2,
        float* __restrict__ out, int b0)
{
    __shared__ __attribute__((aligned(16))) float hb[Sn * HDn];
    __shared__ float wpart[4][Sn];
    __shared__ float psm[Sn];
    int bl = blockIdx.x, t = threadIdx.x;
    for (int i = t; i < Sn * HDn; i += 256) hb[i] = h2[(size_t)bl * (Sn * HDn) + i];
    __syncthreads();

    int u = (t < AHn) ? t : AHn - 1;
    float acc[Sn];
    #pragma unroll
    for (int s = 0; s < Sn; ++s) acc[s] = 0.f;
    for (int k = 0; k < HDn; k += 4) {
        float4 wv = *(const float4*)&WVm[(size_t)u * HDn + k];
        #pragma unroll
        for (int s = 0; s < Sn; ++s) {
            float4 hv = *(const float4*)&hb[s * HDn + k];
            acc[s] += hv.x*wv.x + hv.y*wv.y + hv.z*wv.z + hv.w*wv.w;
        }
    }
    float bias = bV[u];
    float wqv  = wq2[u];
    float mask = (t < AHn) ? 1.f : 0.f;
    int wid = t >> 6;
    #pragma unroll
    for (int s = 0; s < Sn; ++s) {
        float v = tanhf(acc[s] + bias) * wqv * mask;
        #pragma unroll
        for (int off = 32; off > 0; off >>= 1) v += __shfl_xor(v, off);
        if ((t & 63) == 0) wpart[wid][s] = v;
    }
    __syncthreads();
    if (t == 0) {
        float b2 = bq2[0];
        float sc[Sn], mx = -1e30f;
        for (int s = 0; s < Sn; ++s) {
            sc[s] = wpart[0][s] + wpart[1][s] + wpart[2][s] + wpart[3][s] + b2;
            mx = fmaxf(mx, sc[s]);
        }
        float sum = 0.f;
        for (int s = 0; s < Sn; ++s) { float e = expf(sc[s] - mx); psm[s] = e; sum += e; }
        float inv = 1.f / sum;
        for (int s = 0; s < Sn; ++s) psm[s] *= inv;
    }
    __syncthreads();
    for (int e = t; e < HDn; e += 256) {
        float z = 0.f;
        #pragma unroll
        for (int s = 0; s < Sn; ++s) z += psm[s] * hb[s * HDn + e];
        out[(size_t)(b0 + bl) * HDn + e] = z;
    }
}

// ---------------------------------------------------------------------------
extern "C" void kernel_launch(void* const* d_in, const int* in_sizes, int n_in,
                              void* d_out, int out_size, void* d_ws, size_t ws_size,
                              hipStream_t stream)
{
    const int*   x   = (const int*)d_in[0];
    const float* emb = (const float*)d_in[1];
    const float* Wq  = (const float*)d_in[2];
    const float* bq  = (const float*)d_in[3];
    const float* Wv  = (const float*)d_in[4];
    const float* bv  = (const float*)d_in[5];
    const float* WVm = (const float*)d_in[6];
    const float* bV  = (const float*)d_in[7];
    const float* wq2 = (const float*)d_in[8];
    const float* bq2 = (const float*)d_in[9];
    float* outp = (float*)d_out;

    // ws: fixed Wqb bf16 [NP][KP] = 3,850,240 B, then per-chunk region
    const size_t wqbBytes = (size_t)NP * KP * 2;      // 3,850,240
    // per-b: c 36000 + cbf 19200 + xq 720000 + xv 48000 + h2 48000 = 871,200
    size_t wrem = (ws_size > wqbBytes) ? ws_size - wqbBytes : 0;
    int CB = Bn;
    while (CB > 1 && (size_t)CB * 871200ull > wrem) CB >>= 1;

    char* ws = (char*)d_ws;
    unsigned short* Wqb = (unsigned short*)(ws);
    char* wsc = ws + wqbBytes;
    float*          c   = (float*)(wsc);
    unsigned short* cbf = (unsigned short*)(wsc + (size_t)CB * 36000ull);
    float*          xq  = (float*)(wsc + (size_t)CB * 55200ull);
    float*          xv  = (float*)(wsc + (size_t)CB * 775200ull);
    float*          h2  = (float*)(wsc + (size_t)CB * 823200ull);

    k_cast_wq<<<dim3(2048), dim3(256), 0, stream>>>(Wq, Wqb);

    for (int b0 = 0; b0 < Bn; b0 += CB) {
        int nloc = (b0 + CB <= Bn) ? CB : (Bn - b0);
        int Mloc = nloc * Sn;
        int gc = (nloc * Sn * Dm + 255) / 256;
        if (gc > 2048) gc = 2048;
        k_c<<<dim3(gc), dim3(256), 0, stream>>>(x, emb, c, b0, nloc);
        int gcc = (Mloc * KP + 255) / 256;
        if (gcc > 2048) gcc = 2048;
        k_cast_c<<<dim3(gcc), dim3(256), 0, stream>>>(c, cbf, Mloc);
        dim3 gq(NP / 128, (Mloc + 127) / 128);
        k_xqm<<<gq, dim3(256), 0, stream>>>(cbf, Wqb, bq, xq, Mloc);
        k_xv<<<dim3(nloc), dim3(256), 0, stream>>>(c, Wv, bv, xv);
        k_attn<<<dim3(Hn, nloc), dim3(256), 0, stream>>>(c, xq, xv, h2);
        k_pool<<<dim3(nloc), dim3(256), 0, stream>>>(h2, WVm, bV, wq2, bq2, outp, b0);
    }
}

// Round 12
// 773.814 us; speedup vs baseline: 2.2771x; 1.3120x over previous
//
#include <hip/hip_runtime.h>
#include <hip/hip_bf16.h>

#define Bn  512
#define Sn  30
#define Dm  300
#define Hn  20
#define DHn 20
#define AHn 200
#define HDn 400
#define EQn 6000
#define KP  320           // K padded to 10*32
#define NP  6016          // N padded to 47*128
#define KA  328           // bf16 LDS row stride (656B -> bank residue 4, free)

typedef __attribute__((ext_vector_type(8))) short short8;
typedef __attribute__((ext_vector_type(4))) float f32x4;

__device__ __forceinline__ unsigned short f2b(float v) {
    __hip_bfloat16 h = __float2bfloat16(v);
    return *(unsigned short*)&h;
}

// ---------------------------------------------------------------------------
// k_c: c[bl][s][d] = emb[x[b0+bl][s]][d] + PE(s,d)
// ---------------------------------------------------------------------------
__global__ __launch_bounds__(256) void k_c(const int* __restrict__ x,
        const float* __restrict__ emb, float* __restrict__ c, int b0, int nloc)
{
    int n = nloc * Sn * Dm;
    for (int p = blockIdx.x * 256 + threadIdx.x; p < n; p += gridDim.x * 256) {
        int bl = p / (Sn * Dm);
        int r  = p - bl * (Sn * Dm);
        int s = r / Dm, d = r - s * Dm;
        int tok = x[(b0 + bl) * Sn + s];
        float dv = expf(-0.06140226914650789f * (float)(d >> 1));
        float ang = (float)s * dv;
        c[p] = emb[(size_t)tok * Dm + d] + ((d & 1) ? cosf(ang) : sinf(ang));
    }
}

// ---------------------------------------------------------------------------
// k_cast_wq: Wqb[NP][KP] = bf16(Wq[n][k]) zero-padded   (once per launch)
// ---------------------------------------------------------------------------
__global__ __launch_bounds__(256) void k_cast_wq(const float* __restrict__ Wq,
        unsigned short* __restrict__ Wqb)
{
    for (int p = blockIdx.x * 256 + threadIdx.x; p < NP * KP; p += gridDim.x * 256) {
        int nq = p / KP, k = p - nq * KP;
        float v = (nq < EQn && k < Dm) ? Wq[(size_t)nq * Dm + k] : 0.f;
        Wqb[p] = f2b(v);
    }
}

// ---------------------------------------------------------------------------
// k_cast_c: cbf[Mloc][KP] = bf16(c[m][k]) zero-padded   (per chunk)
// ---------------------------------------------------------------------------
__global__ __launch_bounds__(256) void k_cast_c(const float* __restrict__ c,
        unsigned short* __restrict__ cbf, int Mloc)
{
    int n = Mloc * KP;
    for (int p = blockIdx.x * 256 + threadIdx.x; p < n; p += gridDim.x * 256) {
        int m = p / KP, k = p - m * KP;
        float v = (k < Dm) ? c[(size_t)m * Dm + k] : 0.f;
        cbf[p] = f2b(v);
    }
}

// ---------------------------------------------------------------------------
// k_xqm: xq[m][n] = sum_k cbf[m][k]*Wqb[n][k] + bq[n]   (bf16 MFMA, f32 acc)
// ---------------------------------------------------------------------------
__global__ __launch_bounds__(256) void k_xqm(const unsigned short* __restrict__ Ab,
        const unsigned short* __restrict__ Bb, const float* __restrict__ bq,
        float* __restrict__ xq, int Mloc)
{
    __shared__ __attribute__((aligned(16))) unsigned short As[128][72];
    __shared__ __attribute__((aligned(16))) unsigned short Bs[128][72];
    int t = threadIdx.x;
    int l = t & 63, w = t >> 6;
    int wm = w >> 1, wn = w & 1;
    int m0 = blockIdx.y * 128, n0 = blockIdx.x * 128;
    int cl = l & 15, rh = l >> 4;

    f32x4 zero4 = {0.f, 0.f, 0.f, 0.f};
    f32x4 acc[4][4];
    #pragma unroll
    for (int a = 0; a < 4; ++a)
        #pragma unroll
        for (int bb = 0; bb < 4; ++bb) acc[a][bb] = zero4;

    for (int k0 = 0; k0 < KP; k0 += 64) {
        #pragma unroll
        for (int cc = 0; cc < 4; ++cc) {
            int q = t + 256 * cc;
            int row = q >> 3, kc = (q & 7) * 8;
            int gm = m0 + row;
            short8 av = {0, 0, 0, 0, 0, 0, 0, 0};
            if (gm < Mloc) av = *(const short8*)&Ab[(size_t)gm * KP + k0 + kc];
            *(short8*)&As[row][kc] = av;
            short8 bv = *(const short8*)&Bb[(size_t)(n0 + row) * KP + k0 + kc];
            *(short8*)&Bs[row][kc] = bv;
        }
        __syncthreads();
        #pragma unroll
        for (int k2 = 0; k2 < 2; ++k2) {
            int kk = k2 * 32 + rh * 8;
            short8 af[4], bf[4];
            #pragma unroll
            for (int f = 0; f < 4; ++f) {
                af[f] = *(const short8*)&As[wm * 64 + f * 16 + cl][kk];
                bf[f] = *(const short8*)&Bs[wn * 64 + f * 16 + cl][kk];
            }
            #pragma unroll
            for (int mf = 0; mf < 4; ++mf)
                #pragma unroll
                for (int nf = 0; nf < 4; ++nf)
                    acc[mf][nf] = __builtin_amdgcn_mfma_f32_16x16x32_bf16(
                        af[mf], bf[nf], acc[mf][nf], 0, 0, 0);
        }
        __syncthreads();
    }

    #pragma unroll
    for (int nf = 0; nf < 4; ++nf) {
        int gn = n0 + wn * 64 + nf * 16 + cl;
        float bqv = (gn < EQn) ? bq[gn] : 0.f;
        #pragma unroll
        for (int mf = 0; mf < 4; ++mf) {
            int gmb = m0 + wm * 64 + mf * 16 + rh * 4;
            #pragma unroll
            for (int r = 0; r < 4; ++r) {
                int gm = gmb + r;
                if (gm < Mloc && gn < EQn)
                    xq[(size_t)gm * EQn + gn] = acc[mf][nf][r] + bqv;
            }
        }
    }
}

// ---------------------------------------------------------------------------
// k_xv: xv[bl][s][e] = c[bl][s][:].Wv[e][:] + bv[e]
// ---------------------------------------------------------------------------
__global__ __launch_bounds__(256) void k_xv(const float* __restrict__ c,
        const float* __restrict__ Wv, const float* __restrict__ bv,
        float* __restrict__ xv)
{
    __shared__ __attribute__((aligned(16))) float cb[Sn * Dm];
    int bl = blockIdx.x, t = threadIdx.x;
    for (int i = t; i < Sn * Dm; i += 256) cb[i] = c[(size_t)bl * Sn * Dm + i];
    __syncthreads();
    if (t < 200) {
        int e0 = (t % 100) * 4;
        int s0 = (t / 100) * 15;
        float acc[15][4];
        #pragma unroll
        for (int si = 0; si < 15; ++si)
            #pragma unroll
            for (int ee = 0; ee < 4; ++ee) acc[si][ee] = 0.f;
        for (int k = 0; k < Dm; k += 4) {
            float4 w0 = *(const float4*)&Wv[(size_t)(e0 + 0) * Dm + k];
            float4 w1 = *(const float4*)&Wv[(size_t)(e0 + 1) * Dm + k];
            float4 w2 = *(const float4*)&Wv[(size_t)(e0 + 2) * Dm + k];
            float4 w3 = *(const float4*)&Wv[(size_t)(e0 + 3) * Dm + k];
            #pragma unroll
            for (int si = 0; si < 15; ++si) {
                float4 cv = *(const float4*)&cb[(s0 + si) * Dm + k];
                acc[si][0] += cv.x*w0.x + cv.y*w0.y + cv.z*w0.z + cv.w*w0.w;
                acc[si][1] += cv.x*w1.x + cv.y*w1.y + cv.z*w1.z + cv.w*w1.w;
                acc[si][2] += cv.x*w2.x + cv.y*w2.y + cv.z*w2.z + cv.w*w2.w;
                acc[si][3] += cv.x*w3.x + cv.y*w3.y + cv.z*w3.z + cv.w*w3.w;
            }
        }
        #pragma unroll
        for (int si = 0; si < 15; ++si)
            #pragma unroll
            for (int ee = 0; ee < 4; ++ee)
                xv[(size_t)bl * (Sn * HDn) + (s0 + si) * HDn + e0 + ee]
                    = acc[si][ee] + bv[e0 + ee];
    }
}

// ---------------------------------------------------------------------------
// k_attn v2: one block (256 thr = 4 waves) per (h, bl). MFMA scores.
//   Q(i,d) = xq[bl*180000 + h*9000 + i*300 + d]   -> qb[32][KA] bf16 (padded)
//   K(d,j) = c [bl*9000  + d*30 + j]              -> kb[j][d]  bf16 (padded)
//   wave w computes 16x16 score tile (w>>1, w&1) via 10 MFMAs
//   softmax over i per column j (axis=-2); PV in f32
// ---------------------------------------------------------------------------
__global__ __launch_bounds__(256) void k_attn(const float* __restrict__ c,
        const float* __restrict__ xq, const float* __restrict__ xv,
        float* __restrict__ h2)
{
    __shared__ __attribute__((aligned(16))) unsigned short qb[32 * KA];
    __shared__ __attribute__((aligned(16))) unsigned short kb[32 * KA];
    __shared__ float wm_s[32 * 33];
    __shared__ float vm[Sn * DHn];
    __shared__ float part[Sn * 8];
    __shared__ float colv[Sn];
    int h = blockIdx.x, bl = blockIdx.y, t = threadIdx.x;

    // zero the bf16 tiles (covers row/col padding)
    {
        unsigned int* qz = (unsigned int*)qb;
        unsigned int* kz = (unsigned int*)kb;
        for (int p = t; p < 32 * KA / 2; p += 256) { qz[p] = 0u; kz[p] = 0u; }
    }
    __syncthreads();

    const float* qsrc = xq + (size_t)bl * (Sn * EQn) + (size_t)h * (Sn * Dm);
    for (int p = t; p < Sn * Dm; p += 256) {
        int i = p / Dm, d = p - i * Dm;
        qb[i * KA + d] = f2b(qsrc[p]);
    }
    const float* ksrc = c + (size_t)bl * (Sn * Dm);
    for (int p = t; p < Sn * Dm; p += 256) {
        int d = p / Sn, j = p - d * Sn;
        kb[j * KA + d] = f2b(ksrc[p]);
    }
    for (int p = t; p < Sn * DHn; p += 256)
        vm[p] = xv[(size_t)bl * (Sn * HDn) + h * (Sn * DHn) + p];
    __syncthreads();

    // scores via MFMA: wave w -> tile (wmt, wnt)
    {
        int l = t & 63, w = t >> 6;
        int wmt = w >> 1, wnt = w & 1;
        int cl = l & 15, rh = l >> 4;
        f32x4 acc = {0.f, 0.f, 0.f, 0.f};
        #pragma unroll
        for (int ks = 0; ks < 10; ++ks) {
            short8 a = *(const short8*)&qb[(wmt * 16 + cl) * KA + ks * 32 + rh * 8];
            short8 b = *(const short8*)&kb[(wnt * 16 + cl) * KA + ks * 32 + rh * 8];
            acc = __builtin_amdgcn_mfma_f32_16x16x32_bf16(a, b, acc, 0, 0, 0);
        }
        #pragma unroll
        for (int r = 0; r < 4; ++r) {
            int i = wmt * 16 + rh * 4 + r, j = wnt * 16 + cl;
            if (i < Sn && j < Sn) wm_s[i * 33 + j] = acc[r];
        }
    }
    __syncthreads();

    // softmax over query dim i (per column j): 240-wide partials + 30-reduce
    if (t < 240) {
        int j = t % 30, r = t / 30;
        float m = -1e30f;
        for (int i = r; i < Sn; i += 8) m = fmaxf(m, wm_s[i * 33 + j]);
        part[j * 8 + r] = m;
    }
    __syncthreads();
    if (t < Sn) {
        float m = part[t * 8];
        #pragma unroll
        for (int r = 1; r < 8; ++r) m = fmaxf(m, part[t * 8 + r]);
        colv[t] = m;
    }
    __syncthreads();
    if (t < 240) {
        int j = t % 30, r = t / 30;
        float m = colv[j], s = 0.f;
        for (int i = r; i < Sn; i += 8) {
            float e = __expf(wm_s[i * 33 + j] - m);
            wm_s[i * 33 + j] = e; s += e;
        }
        part[j * 8 + r] = s;
    }
    __syncthreads();
    if (t < Sn) {
        float s = 0.f;
        #pragma unroll
        for (int r = 0; r < 8; ++r) s += part[t * 8 + r];
        colv[t] = 1.f / s;
    }
    __syncthreads();
    // fold 1/sum into V (softmax normalizer is per column j = per V row)
    for (int p = t; p < Sn * DHn; p += 256) vm[p] *= colv[p / DHn];
    __syncthreads();

    // PV: h2[bl][h*600 + i*20 + k]
    for (int p = t; p < Sn * DHn; p += 256) {
        int i = p / DHn, k = p - i * DHn;
        float acc = 0.f;
        #pragma unroll
        for (int j = 0; j < Sn; ++j) acc += wm_s[i * 33 + j] * vm[j * DHn + k];
        h2[(size_t)bl * (Sn * HDn) + (size_t)h * (Sn * DHn) + p] = acc;
    }
}

// ---------------------------------------------------------------------------
// k_pool: additive pooling per bl -> out[(b0+bl)][400]  (f32 out)
// ---------------------------------------------------------------------------
__global__ __launch_bounds__(256) void k_pool(const float* __restrict__ h2,
        const float* __restrict__ WVm, const float* __restrict__ bV,
        const float* __restrict__ wq2, const float* __restrict__ bq2,
        float* __restrict__ out, int b0)
{
    __shared__ __attribute__((aligned(16))) float hb[Sn * HDn];
    __shared__ float wpart[4][Sn];
    __shared__ float psm[Sn];
    int bl = blockIdx.x, t = threadIdx.x;
    for (int i = t; i < Sn * HDn; i += 256) hb[i] = h2[(size_t)bl * (Sn * HDn) + i];
    __syncthreads();

    int u = (t < AHn) ? t : AHn - 1;
    float acc[Sn];
    #pragma unroll
    for (int s = 0; s < Sn; ++s) acc[s] = 0.f;
    for (int k = 0; k < HDn; k += 4) {
        float4 wv = *(const float4*)&WVm[(size_t)u * HDn + k];
        #pragma unroll
        for (int s = 0; s < Sn; ++s) {
            float4 hv = *(const float4*)&hb[s * HDn + k];
            acc[s] += hv.x*wv.x + hv.y*wv.y + hv.z*wv.z + hv.w*wv.w;
        }
    }
    float bias = bV[u];
    float wqv  = wq2[u];
    float mask = (t < AHn) ? 1.f : 0.f;
    int wid = t >> 6;
    #pragma unroll
    for (int s = 0; s < Sn; ++s) {
        float v = tanhf(acc[s] + bias) * wqv * mask;
        #pragma unroll
        for (int off = 32; off > 0; off >>= 1) v += __shfl_xor(v, off);
        if ((t & 63) == 0) wpart[wid][s] = v;
    }
    __syncthreads();
    if (t == 0) {
        float b2 = bq2[0];
        float sc[Sn], mx = -1e30f;
        for (int s = 0; s < Sn; ++s) {
            sc[s] = wpart[0][s] + wpart[1][s] + wpart[2][s] + wpart[3][s] + b2;
            mx = fmaxf(mx, sc[s]);
        }
        float sum = 0.f;
        for (int s = 0; s < Sn; ++s) { float e = __expf(sc[s] - mx); psm[s] = e; sum += e; }
        float inv = 1.f / sum;
        for (int s = 0; s < Sn; ++s) psm[s] *= inv;
    }
    __syncthreads();
    for (int e = t; e < HDn; e += 256) {
        float z = 0.f;
        #pragma unroll
        for (int s = 0; s < Sn; ++s) z += psm[s] * hb[s * HDn + e];
        out[(size_t)(b0 + bl) * HDn + e] = z;
    }
}

// ---------------------------------------------------------------------------
extern "C" void kernel_launch(void* const* d_in, const int* in_sizes, int n_in,
                              void* d_out, int out_size, void* d_ws, size_t ws_size,
                              hipStream_t stream)
{
    const int*   x   = (const int*)d_in[0];
    const float* emb = (const float*)d_in[1];
    const float* Wq  = (const float*)d_in[2];
    const float* bq  = (const float*)d_in[3];
    const float* Wv  = (const float*)d_in[4];
    const float* bv  = (const float*)d_in[5];
    const float* WVm = (const float*)d_in[6];
    const float* bV  = (const float*)d_in[7];
    const float* wq2 = (const float*)d_in[8];
    const float* bq2 = (const float*)d_in[9];
    float* outp = (float*)d_out;

    const size_t wqbBytes = (size_t)NP * KP * 2;      // 3,850,240
    size_t wrem = (ws_size > wqbBytes) ? ws_size - wqbBytes : 0;
    int CB = Bn;
    while (CB > 1 && (size_t)CB * 871200ull > wrem) CB >>= 1;

    char* ws = (char*)d_ws;
    unsigned short* Wqb = (unsigned short*)(ws);
    char* wsc = ws + wqbBytes;
    float*          c   = (float*)(wsc);
    unsigned short* cbf = (unsigned short*)(wsc + (size_t)CB * 36000ull);
    float*          xq  = (float*)(wsc + (size_t)CB * 55200ull);
    float*          xv  = (float*)(wsc + (size_t)CB * 775200ull);
    float*          h2  = (float*)(wsc + (size_t)CB * 823200ull);

    k_cast_wq<<<dim3(2048), dim3(256), 0, stream>>>(Wq, Wqb);

    for (int b0 = 0; b0 < Bn; b0 += CB) {
        int nloc = (b0 + CB <= Bn) ? CB : (Bn - b0);
        int Mloc = nloc * Sn;
        int gc = (nloc * Sn * Dm + 255) / 256;
        if (gc > 2048) gc = 2048;
        k_c<<<dim3(gc), dim3(256), 0, stream>>>(x, emb, c, b0, nloc);
        int gcc = (Mloc * KP + 255) / 256;
        if (gcc > 2048) gcc = 2048;
        k_cast_c<<<dim3(gcc), dim3(256), 0, stream>>>(c, cbf, Mloc);
        dim3 gq(NP / 128, (Mloc + 127) / 128);
        k_xqm<<<gq, dim3(256), 0, stream>>>(cbf, Wqb, bq, xq, Mloc);
        k_xv<<<dim3(nloc), dim3(256), 0, stream>>>(c, Wv, bv, xv);
        k_attn<<<dim3(Hn, nloc), dim3(256), 0, stream>>>(c, xq, xv, h2);
        k_pool<<<dim3(nloc), dim3(256), 0, stream>>>(h2, WVm, bV, wq2, bq2, outp, b0);
    }
}

// Round 13
// 565.146 us; speedup vs baseline: 3.1179x; 1.3692x over previous
//
#include <hip/hip_runtime.h>
#include <hip/hip_bf16.h>

#define Bn  512
#define Sn  30
#define Dm  300
#define Hn  20
#define DHn 20
#define AHn 200
#define HDn 400
#define EQn 6000
#define KP  320           // K padded to 10*32
#define NW  6400          // N = 6000 (Wq) + 400 (Wv) = 50*128 exactly
#define KA  328           // bf16 LDS row stride for k_attn

typedef __attribute__((ext_vector_type(8))) short short8;
typedef __attribute__((ext_vector_type(4))) float f32x4;

__device__ __forceinline__ unsigned short f2b(float v) {
    __hip_bfloat16 h = __float2bfloat16(v);
    return *(unsigned short*)&h;
}

// ---------------------------------------------------------------------------
// k_c: c[bl][s][d] = emb[x[b0+bl][s]][d] + PE(s,d)
// ---------------------------------------------------------------------------
__global__ __launch_bounds__(256) void k_c(const int* __restrict__ x,
        const float* __restrict__ emb, float* __restrict__ c, int b0, int nloc)
{
    int n = nloc * Sn * Dm;
    for (int p = blockIdx.x * 256 + threadIdx.x; p < n; p += gridDim.x * 256) {
        int bl = p / (Sn * Dm);
        int r  = p - bl * (Sn * Dm);
        int s = r / Dm, d = r - s * Dm;
        int tok = x[(b0 + bl) * Sn + s];
        float dv = expf(-0.06140226914650789f * (float)(d >> 1));
        float ang = (float)s * dv;
        c[p] = emb[(size_t)tok * Dm + d] + ((d & 1) ? cosf(ang) : sinf(ang));
    }
}

// ---------------------------------------------------------------------------
// k_cast_w: Wb[NW][KP] = bf16([Wq; Wv]) zero-padded    (once per launch)
// ---------------------------------------------------------------------------
__global__ __launch_bounds__(256) void k_cast_w(const float* __restrict__ Wq,
        const float* __restrict__ Wv, unsigned short* __restrict__ Wb)
{
    for (int p = blockIdx.x * 256 + threadIdx.x; p < NW * KP; p += gridDim.x * 256) {
        int nq = p / KP, k = p - nq * KP;
        float v = 0.f;
        if (k < Dm)
            v = (nq < EQn) ? Wq[(size_t)nq * Dm + k]
                           : Wv[(size_t)(nq - EQn) * Dm + k];
        Wb[p] = f2b(v);
    }
}

// ---------------------------------------------------------------------------
// k_cast_c: cbf[Mloc][KP] = bf16(c[m][k]) zero-padded   (per chunk)
// ---------------------------------------------------------------------------
__global__ __launch_bounds__(256) void k_cast_c(const float* __restrict__ c,
        unsigned short* __restrict__ cbf, int Mloc)
{
    int n = Mloc * KP;
    for (int p = blockIdx.x * 256 + threadIdx.x; p < n; p += gridDim.x * 256) {
        int m = p / KP, k = p - m * KP;
        float v = (k < Dm) ? c[(size_t)m * Dm + k] : 0.f;
        cbf[p] = f2b(v);
    }
}

// ---------------------------------------------------------------------------
// k_xqm: [xq | xv][m][n] = sum_k cbf[m][k]*Wb[n][k] + bias   (bf16 MFMA)
// 128x128 tile, 4 waves (2x2 of 64x64), mfma_f32_16x16x32_bf16, BK=64
// epilogue: n < 6000 -> xq (+bq);  n >= 6000 -> xv (+bv)
// ---------------------------------------------------------------------------
__global__ __launch_bounds__(256) void k_xqm(const unsigned short* __restrict__ Ab,
        const unsigned short* __restrict__ Bb, const float* __restrict__ bq,
        const float* __restrict__ bv, float* __restrict__ xq,
        float* __restrict__ xv, int Mloc)
{
    __shared__ __attribute__((aligned(16))) unsigned short As[128][72];
    __shared__ __attribute__((aligned(16))) unsigned short Bs[128][72];
    int t = threadIdx.x;
    int l = t & 63, w = t >> 6;
    int wm = w >> 1, wn = w & 1;
    int m0 = blockIdx.y * 128, n0 = blockIdx.x * 128;
    int cl = l & 15, rh = l >> 4;

    f32x4 zero4 = {0.f, 0.f, 0.f, 0.f};
    f32x4 acc[4][4];
    #pragma unroll
    for (int a = 0; a < 4; ++a)
        #pragma unroll
        for (int bb = 0; bb < 4; ++bb) acc[a][bb] = zero4;

    for (int k0 = 0; k0 < KP; k0 += 64) {
        #pragma unroll
        for (int cc = 0; cc < 4; ++cc) {
            int q = t + 256 * cc;
            int row = q >> 3, kc = (q & 7) * 8;
            int gm = m0 + row;
            short8 av = {0, 0, 0, 0, 0, 0, 0, 0};
            if (gm < Mloc) av = *(const short8*)&Ab[(size_t)gm * KP + k0 + kc];
            *(short8*)&As[row][kc] = av;
            short8 bvv = *(const short8*)&Bb[(size_t)(n0 + row) * KP + k0 + kc];
            *(short8*)&Bs[row][kc] = bvv;
        }
        __syncthreads();
        #pragma unroll
        for (int k2 = 0; k2 < 2; ++k2) {
            int kk = k2 * 32 + rh * 8;
            short8 af[4], bf[4];
            #pragma unroll
            for (int f = 0; f < 4; ++f) {
                af[f] = *(const short8*)&As[wm * 64 + f * 16 + cl][kk];
                bf[f] = *(const short8*)&Bs[wn * 64 + f * 16 + cl][kk];
            }
            #pragma unroll
            for (int mf = 0; mf < 4; ++mf)
                #pragma unroll
                for (int nf = 0; nf < 4; ++nf)
                    acc[mf][nf] = __builtin_amdgcn_mfma_f32_16x16x32_bf16(
                        af[mf], bf[nf], acc[mf][nf], 0, 0, 0);
        }
        __syncthreads();
    }

    // epilogue: C/D mapping col=lane&15, row=(lane>>4)*4+reg  [m89-verified]
    #pragma unroll
    for (int nf = 0; nf < 4; ++nf) {
        int gn = n0 + wn * 64 + nf * 16 + cl;
        float bias = (gn < EQn) ? bq[gn] : bv[gn - EQn];
        #pragma unroll
        for (int mf = 0; mf < 4; ++mf) {
            int gmb = m0 + wm * 64 + mf * 16 + rh * 4;
            #pragma unroll
            for (int r = 0; r < 4; ++r) {
                int gm = gmb + r;
                if (gm < Mloc) {
                    float val = acc[mf][nf][r] + bias;
                    if (gn < EQn) xq[(size_t)gm * EQn + gn] = val;
                    else          xv[(size_t)gm * HDn + (gn - EQn)] = val;
                }
            }
        }
    }
}

// ---------------------------------------------------------------------------
// k_attn: one block (4 waves) per (h, bl). MFMA scores, axis=-2 softmax, PV.
// ---------------------------------------------------------------------------
__global__ __launch_bounds__(256) void k_attn(const float* __restrict__ c,
        const float* __restrict__ xq, const float* __restrict__ xv,
        float* __restrict__ h2)
{
    __shared__ __attribute__((aligned(16))) unsigned short qb[32 * KA];
    __shared__ __attribute__((aligned(16))) unsigned short kb[32 * KA];
    __shared__ float wm_s[32 * 33];
    __shared__ float vm[Sn * DHn];
    __shared__ float part[Sn * 8];
    __shared__ float colv[Sn];
    int h = blockIdx.x, bl = blockIdx.y, t = threadIdx.x;

    {
        unsigned int* qz = (unsigned int*)qb;
        unsigned int* kz = (unsigned int*)kb;
        for (int p = t; p < 32 * KA / 2; p += 256) { qz[p] = 0u; kz[p] = 0u; }
    }
    __syncthreads();

    const float* qsrc = xq + (size_t)bl * (Sn * EQn) + (size_t)h * (Sn * Dm);
    for (int p = t; p < Sn * Dm; p += 256) {
        int i = p / Dm, d = p - i * Dm;
        qb[i * KA + d] = f2b(qsrc[p]);
    }
    const float* ksrc = c + (size_t)bl * (Sn * Dm);
    for (int p = t; p < Sn * Dm; p += 256) {
        int d = p / Sn, j = p - d * Sn;
        kb[j * KA + d] = f2b(ksrc[p]);
    }
    for (int p = t; p < Sn * DHn; p += 256)
        vm[p] = xv[(size_t)bl * (Sn * HDn) + h * (Sn * DHn) + p];
    __syncthreads();

    {
        int l = t & 63, w = t >> 6;
        int wmt = w >> 1, wnt = w & 1;
        int cl = l & 15, rh = l >> 4;
        f32x4 acc = {0.f, 0.f, 0.f, 0.f};
        #pragma unroll
        for (int ks = 0; ks < 10; ++ks) {
            short8 a = *(const short8*)&qb[(wmt * 16 + cl) * KA + ks * 32 + rh * 8];
            short8 b = *(const short8*)&kb[(wnt * 16 + cl) * KA + ks * 32 + rh * 8];
            acc = __builtin_amdgcn_mfma_f32_16x16x32_bf16(a, b, acc, 0, 0, 0);
        }
        #pragma unroll
        for (int r = 0; r < 4; ++r) {
            int i = wmt * 16 + rh * 4 + r, j = wnt * 16 + cl;
            if (i < Sn && j < Sn) wm_s[i * 33 + j] = acc[r];
        }
    }
    __syncthreads();

    // softmax over query dim i (per column j)
    if (t < 240) {
        int j = t % 30, r = t / 30;
        float m = -1e30f;
        for (int i = r; i < Sn; i += 8) m = fmaxf(m, wm_s[i * 33 + j]);
        part[j * 8 + r] = m;
    }
    __syncthreads();
    if (t < Sn) {
        float m = part[t * 8];
        #pragma unroll
        for (int r = 1; r < 8; ++r) m = fmaxf(m, part[t * 8 + r]);
        colv[t] = m;
    }
    __syncthreads();
    if (t < 240) {
        int j = t % 30, r = t / 30;
        float m = colv[j], s = 0.f;
        for (int i = r; i < Sn; i += 8) {
            float e = __expf(wm_s[i * 33 + j] - m);
            wm_s[i * 33 + j] = e; s += e;
        }
        part[j * 8 + r] = s;
    }
    __syncthreads();
    if (t < Sn) {
        float s = 0.f;
        #pragma unroll
        for (int r = 0; r < 8; ++r) s += part[t * 8 + r];
        colv[t] = 1.f / s;
    }
    __syncthreads();
    for (int p = t; p < Sn * DHn; p += 256) vm[p] *= colv[p / DHn];
    __syncthreads();

    for (int p = t; p < Sn * DHn; p += 256) {
        int i = p / DHn, k = p - i * DHn;
        float acc = 0.f;
        #pragma unroll
        for (int j = 0; j < Sn; ++j) acc += wm_s[i * 33 + j] * vm[j * DHn + k];
        h2[(size_t)bl * (Sn * HDn) + (size_t)h * (Sn * DHn) + p] = acc;
    }
}

// ---------------------------------------------------------------------------
// k_pool: additive pooling per bl -> out[(b0+bl)][400]  (f32 out)
// ---------------------------------------------------------------------------
__global__ __launch_bounds__(256) void k_pool(const float* __restrict__ h2,
        const float* __restrict__ WVm, const float* __restrict__ bV,
        const float* __restrict__ wq2, const float* __restrict__ bq2,
        float* __restrict__ out, int b0)
{
    __shared__ __attribute__((aligned(16))) float hb[Sn * HDn];
    __shared__ float wpart[4][Sn];
    __shared__ float psm[Sn];
    int bl = blockIdx.x, t = threadIdx.x;
    for (int i = t; i < Sn * HDn; i += 256) hb[i] = h2[(size_t)bl * (Sn * HDn) + i];
    __syncthreads();

    int u = (t < AHn) ? t : AHn - 1;
    float acc[Sn];
    #pragma unroll
    for (int s = 0; s < Sn; ++s) acc[s] = 0.f;
    for (int k = 0; k < HDn; k += 4) {
        float4 wv = *(const float4*)&WVm[(size_t)u * HDn + k];
        #pragma unroll
        for (int s = 0; s < Sn; ++s) {
            float4 hv = *(const float4*)&hb[s * HDn + k];
            acc[s] += hv.x*wv.x + hv.y*wv.y + hv.z*wv.z + hv.w*wv.w;
        }
    }
    float bias = bV[u];
    float wqv  = wq2[u];
    float mask = (t < AHn) ? 1.f : 0.f;
    int wid = t >> 6;
    #pragma unroll
    for (int s = 0; s < Sn; ++s) {
        float v = tanhf(acc[s] + bias) * wqv * mask;
        #pragma unroll
        for (int off = 32; off > 0; off >>= 1) v += __shfl_xor(v, off);
        if ((t & 63) == 0) wpart[wid][s] = v;
    }
    __syncthreads();
    if (t == 0) {
        float b2 = bq2[0];
        float sc[Sn], mx = -1e30f;
        for (int s = 0; s < Sn; ++s) {
            sc[s] = wpart[0][s] + wpart[1][s] + wpart[2][s] + wpart[3][s] + b2;
            mx = fmaxf(mx, sc[s]);
        }
        float sum = 0.f;
        for (int s = 0; s < Sn; ++s) { float e = __expf(sc[s] - mx); psm[s] = e; sum += e; }
        float inv = 1.f / sum;
        for (int s = 0; s < Sn; ++s) psm[s] *= inv;
    }
    __syncthreads();
    for (int e = t; e < HDn; e += 256) {
        float z = 0.f;
        #pragma unroll
        for (int s = 0; s < Sn; ++s) z += psm[s] * hb[s * HDn + e];
        out[(size_t)(b0 + bl) * HDn + e] = z;
    }
}

// ---------------------------------------------------------------------------
extern "C" void kernel_launch(void* const* d_in, const int* in_sizes, int n_in,
                              void* d_out, int out_size, void* d_ws, size_t ws_size,
                              hipStream_t stream)
{
    const int*   x   = (const int*)d_in[0];
    const float* emb = (const float*)d_in[1];
    const float* Wq  = (const float*)d_in[2];
    const float* bq  = (const float*)d_in[3];
    const float* Wv  = (const float*)d_in[4];
    const float* bv  = (const float*)d_in[5];
    const float* WVm = (const float*)d_in[6];
    const float* bV  = (const float*)d_in[7];
    const float* wq2 = (const float*)d_in[8];
    const float* bq2 = (const float*)d_in[9];
    float* outp = (float*)d_out;

    const size_t wbBytes = (size_t)NW * KP * 2;       // 4,096,000
    // per-b: c 36000 + cbf 19200 + xq 720000 + xv 48000 + h2 48000 = 871,200
    size_t wrem = (ws_size > wbBytes) ? ws_size - wbBytes : 0;
    int CB = Bn;
    while (CB > 1 && (size_t)CB * 871200ull > wrem) CB >>= 1;

    char* ws = (char*)d_ws;
    unsigned short* Wb  = (unsigned short*)(ws);
    char* wsc = ws + wbBytes;
    float*          c   = (float*)(wsc);
    unsigned short* cbf = (unsigned short*)(wsc + (size_t)CB * 36000ull);
    float*          xq  = (float*)(wsc + (size_t)CB * 55200ull);
    float*          xv  = (float*)(wsc + (size_t)CB * 775200ull);
    float*          h2  = (float*)(wsc + (size_t)CB * 823200ull);

    k_cast_w<<<dim3(2048), dim3(256), 0, stream>>>(Wq, Wv, Wb);

    for (int b0 = 0; b0 < Bn; b0 += CB) {
        int nloc = (b0 + CB <= Bn) ? CB : (Bn - b0);
        int Mloc = nloc * Sn;
        int gc = (nloc * Sn * Dm + 255) / 256;
        if (gc > 2048) gc = 2048;
        k_c<<<dim3(gc), dim3(256), 0, stream>>>(x, emb, c, b0, nloc);
        int gcc = (Mloc * KP + 255) / 256;
        if (gcc > 2048) gcc = 2048;
        k_cast_c<<<dim3(gcc), dim3(256), 0, stream>>>(c, cbf, Mloc);
        dim3 gq(NW / 128, (Mloc + 127) / 128);
        k_xqm<<<gq, dim3(256), 0, stream>>>(cbf, Wb, bq, bv, xq, xv, Mloc);
        k_attn<<<dim3(Hn, nloc), dim3(256), 0, stream>>>(c, xq, xv, h2);
        k_pool<<<dim3(nloc), dim3(256), 0, stream>>>(h2, WVm, bV, wq2, bq2, outp, b0);
    }
}

// Round 14
// 372.147 us; speedup vs baseline: 4.7349x; 1.5186x over previous
//
#include <hip/hip_runtime.h>
#include <hip/hip_bf16.h>

#define Bn  512
#define Sn  30
#define Dm  300
#define Hn  20
#define DHn 20
#define AHn 200
#define HDn 400
#define EQn 6000
#define KP  320           // K padded to 10*32
#define NW  6400          // N = 6000 (Wq) + 400 (Wv) = 50*128 exactly
#define KA  328           // bf16 LDS row stride for k_attn

typedef __attribute__((ext_vector_type(8))) short short8;
typedef __attribute__((ext_vector_type(4))) float f32x4;

__device__ __forceinline__ unsigned short f2b(float v) {
    __hip_bfloat16 h = __float2bfloat16(v);
    return *(unsigned short*)&h;
}
__device__ __forceinline__ float b2f(unsigned short u) {
    union { unsigned int i; float f; } cv; cv.i = ((unsigned int)u) << 16; return cv.f;
}

// ---------------------------------------------------------------------------
// k_c: c[bl][s][d] = emb[..] + PE(s,d); also writes bf16 cbf[m][KP] (padded)
// ---------------------------------------------------------------------------
__global__ __launch_bounds__(256) void k_c(const int* __restrict__ x,
        const float* __restrict__ emb, float* __restrict__ c,
        unsigned short* __restrict__ cbf, int b0, int nloc)
{
    int n = nloc * Sn * Dm;
    for (int p = blockIdx.x * 256 + threadIdx.x; p < n; p += gridDim.x * 256) {
        int bl = p / (Sn * Dm);
        int r  = p - bl * (Sn * Dm);
        int s = r / Dm, d = r - s * Dm;
        int tok = x[(b0 + bl) * Sn + s];
        float dv = expf(-0.06140226914650789f * (float)(d >> 1));
        float ang = (float)s * dv;
        float val = emb[(size_t)tok * Dm + d] + ((d & 1) ? cosf(ang) : sinf(ang));
        c[p] = val;
        cbf[(size_t)(bl * Sn + s) * KP + d] = f2b(val);
    }
    // zero the K-pad region of cbf
    int npad = nloc * Sn * (KP - Dm);
    for (int p = blockIdx.x * 256 + threadIdx.x; p < npad; p += gridDim.x * 256) {
        int m = p / (KP - Dm), k = Dm + p % (KP - Dm);
        cbf[(size_t)m * KP + k] = 0;
    }
}

// ---------------------------------------------------------------------------
// k_cast_w: Wb[NW][KP] = bf16([Wq; Wv]) zero-padded    (once per launch)
// ---------------------------------------------------------------------------
__global__ __launch_bounds__(256) void k_cast_w(const float* __restrict__ Wq,
        const float* __restrict__ Wv, unsigned short* __restrict__ Wb)
{
    for (int p = blockIdx.x * 256 + threadIdx.x; p < NW * KP; p += gridDim.x * 256) {
        int nq = p / KP, k = p - nq * KP;
        float v = 0.f;
        if (k < Dm)
            v = (nq < EQn) ? Wq[(size_t)nq * Dm + k]
                           : Wv[(size_t)(nq - EQn) * Dm + k];
        Wb[p] = f2b(v);
    }
}

// ---------------------------------------------------------------------------
// k_xqm: [xqb | xvb][m][n] = bf16(sum_k cbf[m][k]*Wb[n][k] + bias)
// 128x128 tile, 4 waves, mfma_f32_16x16x32_bf16, BK=64.
// Epilogue: acc -> Cs (LDS, aliases As/Bs) -> coalesced 16B global stores.
// 1D grid with bijective XCD-chunked swizzle (m204).
// ---------------------------------------------------------------------------
__global__ __launch_bounds__(256) void k_xqm(const unsigned short* __restrict__ Ab,
        const unsigned short* __restrict__ Bb, const float* __restrict__ bq,
        const float* __restrict__ bv, unsigned short* __restrict__ xqb,
        unsigned short* __restrict__ xvb, int Mloc, int mtiles)
{
    __shared__ __attribute__((aligned(16))) char smem[36864];
    unsigned short (*As)[72] = (unsigned short (*)[72])smem;
    unsigned short (*Bs)[72] = (unsigned short (*)[72])(smem + 18432);
    unsigned short (*Cs)[136] = (unsigned short (*)[136])smem;   // 34816 B

    // bijective XCD swizzle
    int nwg = 50 * mtiles;
    int bid = blockIdx.x;
    int q8 = nwg >> 3, r8 = nwg & 7;
    int xcd = bid & 7, idx = bid >> 3;
    int wg = (xcd < r8 ? xcd * (q8 + 1) : r8 * (q8 + 1) + (xcd - r8) * q8) + idx;
    int bx = wg % 50, by = wg / 50;

    int t = threadIdx.x;
    int l = t & 63, w = t >> 6;
    int wm = w >> 1, wn = w & 1;
    int m0 = by * 128, n0 = bx * 128;
    int cl = l & 15, rh = l >> 4;

    f32x4 zero4 = {0.f, 0.f, 0.f, 0.f};
    f32x4 acc[4][4];
    #pragma unroll
    for (int a = 0; a < 4; ++a)
        #pragma unroll
        for (int bb = 0; bb < 4; ++bb) acc[a][bb] = zero4;

    for (int k0 = 0; k0 < KP; k0 += 64) {
        #pragma unroll
        for (int cc = 0; cc < 4; ++cc) {
            int qq = t + 256 * cc;
            int row = qq >> 3, kc = (qq & 7) * 8;
            int gm = m0 + row;
            short8 av = {0, 0, 0, 0, 0, 0, 0, 0};
            if (gm < Mloc) av = *(const short8*)&Ab[(size_t)gm * KP + k0 + kc];
            *(short8*)&As[row][kc] = av;
            short8 bvv = *(const short8*)&Bb[(size_t)(n0 + row) * KP + k0 + kc];
            *(short8*)&Bs[row][kc] = bvv;
        }
        __syncthreads();
        #pragma unroll
        for (int k2 = 0; k2 < 2; ++k2) {
            int kk = k2 * 32 + rh * 8;
            short8 af[4], bf[4];
            #pragma unroll
            for (int f = 0; f < 4; ++f) {
                af[f] = *(const short8*)&As[wm * 64 + f * 16 + cl][kk];
                bf[f] = *(const short8*)&Bs[wn * 64 + f * 16 + cl][kk];
            }
            #pragma unroll
            for (int mf = 0; mf < 4; ++mf)
                #pragma unroll
                for (int nf = 0; nf < 4; ++nf)
                    acc[mf][nf] = __builtin_amdgcn_mfma_f32_16x16x32_bf16(
                        af[mf], bf[nf], acc[mf][nf], 0, 0, 0);
        }
        __syncthreads();
    }

    // epilogue 1: acc -> Cs bf16 (C/D map col=lane&15, row=(lane>>4)*4+reg)
    #pragma unroll
    for (int nf = 0; nf < 4; ++nf) {
        int gn = n0 + wn * 64 + nf * 16 + cl;
        float bias = (gn < EQn) ? bq[gn] : bv[gn - EQn];
        #pragma unroll
        for (int mf = 0; mf < 4; ++mf) {
            int lrow = wm * 64 + mf * 16 + rh * 4;
            #pragma unroll
            for (int r = 0; r < 4; ++r)
                Cs[lrow + r][wn * 64 + nf * 16 + cl] = f2b(acc[mf][nf][r] + bias);
        }
    }
    __syncthreads();

    // epilogue 2: coalesced stores, 16B chunks; 6000 % 8 == 0 -> no straddle
    for (int ch = t; ch < 128 * 16; ch += 256) {
        int row = ch >> 4, colc = (ch & 15) * 8;
        int gm = m0 + row;
        if (gm >= Mloc) continue;
        short8 v = *(const short8*)&Cs[row][colc];
        int gn = n0 + colc;
        if (gn < EQn) *(short8*)&xqb[(size_t)gm * EQn + gn] = v;
        else          *(short8*)&xvb[(size_t)gm * HDn + (gn - EQn)] = v;
    }
}

// ---------------------------------------------------------------------------
// k_attn: one block (4 waves) per (h, bl). MFMA scores, axis=-2 softmax, PV.
// Q from bf16 xqb (direct copy); K from f32 c (cast); V from bf16 xvb.
// ---------------------------------------------------------------------------
__global__ __launch_bounds__(256) void k_attn(const float* __restrict__ c,
        const unsigned short* __restrict__ xqb, const unsigned short* __restrict__ xvb,
        float* __restrict__ h2)
{
    __shared__ __attribute__((aligned(16))) unsigned short qb[32 * KA];
    __shared__ __attribute__((aligned(16))) unsigned short kb[32 * KA];
    __shared__ float wm_s[32 * 33];
    __shared__ float vm[Sn * DHn];
    __shared__ float part[Sn * 8];
    __shared__ float colv[Sn];
    int h = blockIdx.x, bl = blockIdx.y, t = threadIdx.x;

    {
        unsigned int* qz = (unsigned int*)qb;
        unsigned int* kz = (unsigned int*)kb;
        for (int p = t; p < 32 * KA / 2; p += 256) { qz[p] = 0u; kz[p] = 0u; }
    }
    __syncthreads();

    const unsigned short* qsrc = xqb + (size_t)bl * (Sn * EQn) + (size_t)h * (Sn * Dm);
    for (int p = t; p < Sn * Dm; p += 256) {
        int i = p / Dm, d = p - i * Dm;
        qb[i * KA + d] = qsrc[p];
    }
    const float* ksrc = c + (size_t)bl * (Sn * Dm);
    for (int p = t; p < Sn * Dm; p += 256) {
        int d = p / Sn, j = p - d * Sn;
        kb[j * KA + d] = f2b(ksrc[p]);
    }
    for (int p = t; p < Sn * DHn; p += 256)
        vm[p] = b2f(xvb[(size_t)bl * (Sn * HDn) + h * (Sn * DHn) + p]);
    __syncthreads();

    {
        int l = t & 63, w = t >> 6;
        int wmt = w >> 1, wnt = w & 1;
        int cl = l & 15, rh = l >> 4;
        f32x4 acc = {0.f, 0.f, 0.f, 0.f};
        #pragma unroll
        for (int ks = 0; ks < 10; ++ks) {
            short8 a = *(const short8*)&qb[(wmt * 16 + cl) * KA + ks * 32 + rh * 8];
            short8 b = *(const short8*)&kb[(wnt * 16 + cl) * KA + ks * 32 + rh * 8];
            acc = __builtin_amdgcn_mfma_f32_16x16x32_bf16(a, b, acc, 0, 0, 0);
        }
        #pragma unroll
        for (int r = 0; r < 4; ++r) {
            int i = wmt * 16 + rh * 4 + r, j = wnt * 16 + cl;
            if (i < Sn && j < Sn) wm_s[i * 33 + j] = acc[r];
        }
    }
    __syncthreads();

    // softmax over query dim i (per column j)
    if (t < 240) {
        int j = t % 30, r = t / 30;
        float m = -1e30f;
        for (int i = r; i < Sn; i += 8) m = fmaxf(m, wm_s[i * 33 + j]);
        part[j * 8 + r] = m;
    }
    __syncthreads();
    if (t < Sn) {
        float m = part[t * 8];
        #pragma unroll
        for (int r = 1; r < 8; ++r) m = fmaxf(m, part[t * 8 + r]);
        colv[t] = m;
    }
    __syncthreads();
    if (t < 240) {
        int j = t % 30, r = t / 30;
        float m = colv[j], s = 0.f;
        for (int i = r; i < Sn; i += 8) {
            float e = __expf(wm_s[i * 33 + j] - m);
            wm_s[i * 33 + j] = e; s += e;
        }
        part[j * 8 + r] = s;
    }
    __syncthreads();
    if (t < Sn) {
        float s = 0.f;
        #pragma unroll
        for (int r = 0; r < 8; ++r) s += part[t * 8 + r];
        colv[t] = 1.f / s;
    }
    __syncthreads();
    for (int p = t; p < Sn * DHn; p += 256) vm[p] *= colv[p / DHn];
    __syncthreads();

    for (int p = t; p < Sn * DHn; p += 256) {
        int i = p / DHn, k = p - i * DHn;
        float acc = 0.f;
        #pragma unroll
        for (int j = 0; j < Sn; ++j) acc += wm_s[i * 33 + j] * vm[j * DHn + k];
        h2[(size_t)bl * (Sn * HDn) + (size_t)h * (Sn * DHn) + p] = acc;
    }
}

// ---------------------------------------------------------------------------
// k_pool: additive pooling per bl -> out[(b0+bl)][400]  (f32 out)
// ---------------------------------------------------------------------------
__global__ __launch_bounds__(256) void k_pool(const float* __restrict__ h2,
        const float* __restrict__ WVm, const float* __restrict__ bV,
        const float* __restrict__ wq2, const float* __restrict__ bq2,
        float* __restrict__ out, int b0)
{
    __shared__ __attribute__((aligned(16))) float hb[Sn * HDn];
    __shared__ float wpart[4][Sn];
    __shared__ float psm[Sn];
    int bl = blockIdx.x, t = threadIdx.x;
    for (int i = t; i < Sn * HDn; i += 256) hb[i] = h2[(size_t)bl * (Sn * HDn) + i];
    __syncthreads();

    int u = (t < AHn) ? t : AHn - 1;
    float acc[Sn];
    #pragma unroll
    for (int s = 0; s < Sn; ++s) acc[s] = 0.f;
    for (int k = 0; k < HDn; k += 4) {
        float4 wv = *(const float4*)&WVm[(size_t)u * HDn + k];
        #pragma unroll
        for (int s = 0; s < Sn; ++s) {
            float4 hv = *(const float4*)&hb[s * HDn + k];
            acc[s] += hv.x*wv.x + hv.y*wv.y + hv.z*wv.z + hv.w*wv.w;
        }
    }
    float bias = bV[u];
    float wqv  = wq2[u];
    float mask = (t < AHn) ? 1.f : 0.f;
    int wid = t >> 6;
    #pragma unroll
    for (int s = 0; s < Sn; ++s) {
        float v = tanhf(acc[s] + bias) * wqv * mask;
        #pragma unroll
        for (int off = 32; off > 0; off >>= 1) v += __shfl_xor(v, off);
        if ((t & 63) == 0) wpart[wid][s] = v;
    }
    __syncthreads();
    if (t == 0) {
        float b2 = bq2[0];
        float sc[Sn], mx = -1e30f;
        for (int s = 0; s < Sn; ++s) {
            sc[s] = wpart[0][s] + wpart[1][s] + wpart[2][s] + wpart[3][s] + b2;
            mx = fmaxf(mx, sc[s]);
        }
        float sum = 0.f;
        for (int s = 0; s < Sn; ++s) { float e = __expf(sc[s] - mx); psm[s] = e; sum += e; }
        float inv = 1.f / sum;
        for (int s = 0; s < Sn; ++s) psm[s] *= inv;
    }
    __syncthreads();
    for (int e = t; e < HDn; e += 256) {
        float z = 0.f;
        #pragma unroll
        for (int s = 0; s < Sn; ++s) z += psm[s] * hb[s * HDn + e];
        out[(size_t)(b0 + bl) * HDn + e] = z;
    }
}

// ---------------------------------------------------------------------------
extern "C" void kernel_launch(void* const* d_in, const int* in_sizes, int n_in,
                              void* d_out, int out_size, void* d_ws, size_t ws_size,
                              hipStream_t stream)
{
    const int*   x   = (const int*)d_in[0];
    const float* emb = (const float*)d_in[1];
    const float* Wq  = (const float*)d_in[2];
    const float* bq  = (const float*)d_in[3];
    const float* Wv  = (const float*)d_in[4];
    const float* bv  = (const float*)d_in[5];
    const float* WVm = (const float*)d_in[6];
    const float* bV  = (const float*)d_in[7];
    const float* wq2 = (const float*)d_in[8];
    const float* bq2 = (const float*)d_in[9];
    float* outp = (float*)d_out;

    const size_t wbBytes = (size_t)NW * KP * 2;       // 4,096,000
    // per-b: c 36000 + cbf 19200 + xqb 360000 + xvb 24000 + h2 48000 = 487,200
    size_t wrem = (ws_size > wbBytes) ? ws_size - wbBytes : 0;
    int CB = Bn;
    while (CB > 1 && (size_t)CB * 487200ull > wrem) CB >>= 1;

    char* ws = (char*)d_ws;
    unsigned short* Wb  = (unsigned short*)(ws);
    char* wsc = ws + wbBytes;
    float*          c   = (float*)(wsc);
    unsigned short* cbf = (unsigned short*)(wsc + (size_t)CB * 36000ull);
    unsigned short* xqb = (unsigned short*)(wsc + (size_t)CB * 55200ull);
    unsigned short* xvb = (unsigned short*)(wsc + (size_t)CB * 415200ull);
    float*          h2  = (float*)(wsc + (size_t)CB * 439200ull);

    k_cast_w<<<dim3(2048), dim3(256), 0, stream>>>(Wq, Wv, Wb);

    for (int b0 = 0; b0 < Bn; b0 += CB) {
        int nloc = (b0 + CB <= Bn) ? CB : (Bn - b0);
        int Mloc = nloc * Sn;
        int mtiles = (Mloc + 127) / 128;
        int gc = (nloc * Sn * Dm + 255) / 256;
        if (gc > 2048) gc = 2048;
        k_c<<<dim3(gc), dim3(256), 0, stream>>>(x, emb, c, cbf, b0, nloc);
        k_xqm<<<dim3(50 * mtiles), dim3(256), 0, stream>>>(cbf, Wb, bq, bv,
                                                           xqb, xvb, Mloc, mtiles);
        k_attn<<<dim3(Hn, nloc), dim3(256), 0, stream>>>(c, xqb, xvb, h2);
        k_pool<<<dim3(nloc), dim3(256), 0, stream>>>(h2, WVm, bV, wq2, bq2, outp, b0);
    }
}